// Round 1
// baseline (252.199 us; speedup 1.0000x reference)
//
#include <hip/hip_runtime.h>

// Problem constants (fixed by setup_inputs)
constexpr int kC     = 21;
constexpr int kHW    = 512 * 512;        // 262144
constexpr int kB     = 8;
constexpr int kN     = kB * kHW;         // 2,097,152 pixels
constexpr int kQuads = kN / 4;           // 524,288 float4-groups
constexpr int kBlock = 256;
constexpr int kGrid  = kQuads / kBlock;  // 2048 blocks

__global__ void fl_zero(float* out) {
    if (threadIdx.x == 0) out[0] = 0.0f;
}

// One thread = 4 consecutive pixels (same b, consecutive hw).
// For each channel c, the wave's 64 lanes load 64 consecutive float4s ->
// 1 KiB fully-coalesced per instruction. Online softmax keeps register
// pressure low (no 21-element tile).
__global__ __launch_bounds__(kBlock) void fl_main(const float* __restrict__ x,
                                                  const int* __restrict__ tgt,
                                                  float* __restrict__ out) {
    const int gid = blockIdx.x * kBlock + threadIdx.x;   // quad index
    const int b   = gid >> 16;                           // gid / (kHW/4), kHW/4 = 65536
    const int hw4 = gid & 0xFFFF;

    const float* xb = x + (size_t)b * ((size_t)kC * kHW) + (size_t)hw4 * 4;

    // targets: pixel linear index p0 = gid*4 (since b*kHW + hw4*4 == gid*4)
    int4 t4 = *reinterpret_cast<const int4*>(tgt + (size_t)gid * 4);
    // remap 255 -> 0 (kept for reference fidelity; mask afterwards is all-ones)
    const int t0 = (t4.x == 255) ? 0 : t4.x;
    const int t1 = (t4.y == 255) ? 0 : t4.y;
    const int t2 = (t4.z == 255) ? 0 : t4.z;
    const int t3 = (t4.w == 255) ? 0 : t4.w;

    float m0 = -1e30f, m1 = -1e30f, m2 = -1e30f, m3 = -1e30f;
    float s0 = 0.f, s1 = 0.f, s2 = 0.f, s3 = 0.f;
    float xt0 = 0.f, xt1 = 0.f, xt2 = 0.f, xt3 = 0.f;

#pragma unroll
    for (int c = 0; c < kC; ++c) {
        const float4 v = *reinterpret_cast<const float4*>(xb + (size_t)c * kHW);
        {
            float nm = fmaxf(m0, v.x);
            s0 = s0 * __expf(m0 - nm) + __expf(v.x - nm);
            m0 = nm;
            if (c == t0) xt0 = v.x;
        }
        {
            float nm = fmaxf(m1, v.y);
            s1 = s1 * __expf(m1 - nm) + __expf(v.y - nm);
            m1 = nm;
            if (c == t1) xt1 = v.y;
        }
        {
            float nm = fmaxf(m2, v.z);
            s2 = s2 * __expf(m2 - nm) + __expf(v.z - nm);
            m2 = nm;
            if (c == t2) xt2 = v.z;
        }
        {
            float nm = fmaxf(m3, v.w);
            s3 = s3 * __expf(m3 - nm) + __expf(v.w - nm);
            m3 = nm;
            if (c == t3) xt3 = v.w;
        }
    }

    float loss = 0.f;
    {
        float lp = xt0 - m0 - __logf(s0);
        float pt = __expf(lp);
        float o  = 1.f - pt;
        loss += o * o * (-lp);
    }
    {
        float lp = xt1 - m1 - __logf(s1);
        float pt = __expf(lp);
        float o  = 1.f - pt;
        loss += o * o * (-lp);
    }
    {
        float lp = xt2 - m2 - __logf(s2);
        float pt = __expf(lp);
        float o  = 1.f - pt;
        loss += o * o * (-lp);
    }
    {
        float lp = xt3 - m3 - __logf(s3);
        float pt = __expf(lp);
        float o  = 1.f - pt;
        loss += o * o * (-lp);
    }
    loss *= (1.0f / (float)kN);   // prescale so atomic sum IS the mean

    // wave(64) shuffle reduction
#pragma unroll
    for (int off = 32; off > 0; off >>= 1)
        loss += __shfl_down(loss, off, 64);

    __shared__ float ws[kBlock / 64];
    const int lane = threadIdx.x & 63;
    const int wid  = threadIdx.x >> 6;
    if (lane == 0) ws[wid] = loss;
    __syncthreads();
    if (threadIdx.x == 0) {
        atomicAdd(out, ws[0] + ws[1] + ws[2] + ws[3]);
    }
}

extern "C" void kernel_launch(void* const* d_in, const int* in_sizes, int n_in,
                              void* d_out, int out_size, void* d_ws, size_t ws_size,
                              hipStream_t stream) {
    const float* x   = (const float*)d_in[0];
    const int*   tgt = (const int*)d_in[1];
    float*       out = (float*)d_out;

    fl_zero<<<1, 1, 0, stream>>>(out);                 // d_out is poisoned 0xAA
    fl_main<<<kGrid, kBlock, 0, stream>>>(x, tgt, out);
}

// Round 3
// 242.900 us; speedup vs baseline: 1.0383x; 1.0383x over previous
//
#include <hip/hip_runtime.h>

// Problem constants (fixed by setup_inputs)
constexpr int kC     = 21;
constexpr int kHW    = 512 * 512;        // 262144
constexpr int kB     = 8;
constexpr int kN     = kB * kHW;         // 2,097,152 pixels
constexpr int kQuads = kN / 4;           // 524,288 float4-groups
constexpr int kBlock = 256;
constexpr int kGrid  = kQuads / kBlock;  // 2048 blocks

// Native clang vector types — __builtin_nontemporal_load requires these
// (HIP's float4/int4 are structs and are rejected).
typedef float fvec4 __attribute__((ext_vector_type(4)));
typedef int   ivec4 __attribute__((ext_vector_type(4)));

__global__ void fl_zero(float* out) {
    if (threadIdx.x == 0) out[0] = 0.0f;
}

// One thread = 4 consecutive pixels (same b, consecutive hw).
// Two-pass softmax entirely in registers: all 21 channel float4s are loaded
// up-front (independent, fully in flight -> one waitcnt), then a pure-VALU
// max-tree + single-exp-per-channel sum. This removes the 21-step serial
// online-softmax dependency chain and halves the exp count vs R1.
__global__ __launch_bounds__(kBlock) void fl_main(const float* __restrict__ x,
                                                  const int* __restrict__ tgt,
                                                  float* __restrict__ out) {
    const int gid = blockIdx.x * kBlock + threadIdx.x;   // quad index
    const int b   = gid >> 16;                           // gid / 65536
    const int hw4 = gid & 0xFFFF;

    const float* xb = x + (size_t)b * ((size_t)kC * kHW) + (size_t)hw4 * 4;

    // targets: pixel linear index p0 = gid*4
    ivec4 t4 = __builtin_nontemporal_load(
        reinterpret_cast<const ivec4*>(tgt + (size_t)gid * 4));
    int tt[4];
#pragma unroll
    for (int p = 0; p < 4; ++p)
        tt[p] = (t4[p] == 255) ? 0 : t4[p];   // remap 255->0 (reference fidelity)

    // Load all 21 channels (4 pixels each) into registers. Streaming data,
    // zero reuse -> nontemporal.
    fvec4 v[kC];
#pragma unroll
    for (int c = 0; c < kC; ++c) {
        v[c] = __builtin_nontemporal_load(
            reinterpret_cast<const fvec4*>(xb + (size_t)c * kHW));
    }

    float loss = 0.f;
#pragma unroll
    for (int p = 0; p < 4; ++p) {
        const int t = tt[p];

        // max over channels (unrolled fmax chain; compiler builds a tree)
        float m = v[0][p];
#pragma unroll
        for (int c = 1; c < kC; ++c) m = fmaxf(m, v[c][p]);

        // sum of exps; grab x_t and e_t = exp(x_t - m) on the way
        float s = 0.f, et = 0.f, xt = 0.f;
#pragma unroll
        for (int c = 0; c < kC; ++c) {
            const float xv = v[c][p];
            const float e  = __expf(xv - m);
            s += e;
            if (c == t) { et = e; xt = xv; }
        }

        const float logpt = xt - m - __logf(s);
        const float pt    = __fdividef(et, s);   // = exp(logpt), reuses e_t
        const float om    = 1.f - pt;
        loss += om * om * (-logpt);
    }
    loss *= (1.0f / (float)kN);   // prescale so atomic sum IS the mean

    // wave(64) shuffle reduction
#pragma unroll
    for (int off = 32; off > 0; off >>= 1)
        loss += __shfl_down(loss, off, 64);

    __shared__ float ws[kBlock / 64];
    const int lane = threadIdx.x & 63;
    const int wid  = threadIdx.x >> 6;
    if (lane == 0) ws[wid] = loss;
    __syncthreads();
    if (threadIdx.x == 0) {
        atomicAdd(out, ws[0] + ws[1] + ws[2] + ws[3]);
    }
}

extern "C" void kernel_launch(void* const* d_in, const int* in_sizes, int n_in,
                              void* d_out, int out_size, void* d_ws, size_t ws_size,
                              hipStream_t stream) {
    const float* x   = (const float*)d_in[0];
    const int*   tgt = (const int*)d_in[1];
    float*       out = (float*)d_out;

    fl_zero<<<1, 1, 0, stream>>>(out);                 // d_out is poisoned 0xAA
    fl_main<<<kGrid, kBlock, 0, stream>>>(x, tgt, out);
}

// Round 4
// 241.756 us; speedup vs baseline: 1.0432x; 1.0047x over previous
//
#include <hip/hip_runtime.h>

// Problem constants (fixed by setup_inputs)
constexpr int kC     = 21;
constexpr int kHW    = 512 * 512;        // 262144
constexpr int kB     = 8;
constexpr int kN     = kB * kHW;         // 2,097,152 pixels
constexpr int kQuads = kN / 4;           // 524,288 float4-groups
constexpr int kBlock = 256;
constexpr int kGrid  = kQuads / kBlock;  // 2048 blocks

// Native clang vector types — __builtin_nontemporal_load requires these
// (HIP's float4/int4 are structs and are rejected).
typedef float fvec4 __attribute__((ext_vector_type(4)));
typedef int   ivec4 __attribute__((ext_vector_type(4)));

// One thread = 4 consecutive pixels (same b, consecutive hw).
// Two-pass softmax entirely in registers: all 21 channel float4s loaded
// up-front (independent, one waitcnt), then pure-VALU max-tree +
// single-exp-per-channel sum. Only x_t is tracked through the loop
// (1 cmp + 1 cndmask per channel); pt recomputed as exp(logpt) in the
// epilogue (4 extra exps per thread << 84 removed selects + 4 divides).
__global__ __launch_bounds__(kBlock) void fl_main(const float* __restrict__ x,
                                                  const int* __restrict__ tgt,
                                                  float* __restrict__ out) {
    const int gid = blockIdx.x * kBlock + threadIdx.x;   // quad index
    const int b   = gid >> 16;                           // gid / 65536
    const int hw4 = gid & 0xFFFF;

    const float* xb = x + (size_t)b * ((size_t)kC * kHW) + (size_t)hw4 * 4;

    // targets: pixel linear index p0 = gid*4
    ivec4 t4 = __builtin_nontemporal_load(
        reinterpret_cast<const ivec4*>(tgt + (size_t)gid * 4));

    // Load all 21 channels (4 pixels each) into registers. Streaming,
    // zero reuse -> nontemporal.
    fvec4 v[kC];
#pragma unroll
    for (int c = 0; c < kC; ++c) {
        v[c] = __builtin_nontemporal_load(
            reinterpret_cast<const fvec4*>(xb + (size_t)c * kHW));
    }

    float loss = 0.f;
#pragma unroll
    for (int p = 0; p < 4; ++p) {
        const int t = (t4[p] == 255) ? 0 : t4[p];   // remap 255->0 (fidelity)

        // max over channels
        float m = v[0][p];
#pragma unroll
        for (int c = 1; c < kC; ++c) m = fmaxf(m, v[c][p]);

        // sum of exps; track x_t with one select per channel
        float s = 0.f, xt = v[0][p];
#pragma unroll
        for (int c = 0; c < kC; ++c) {
            const float xv = v[c][p];
            s += __expf(xv - m);
            if (c == t) xt = xv;
        }

        const float logpt = xt - m - __logf(s);
        const float pt    = __expf(logpt);
        const float om    = 1.f - pt;
        loss += om * om * (-logpt);
    }
    loss *= (1.0f / (float)kN);   // prescale so atomic sum IS the mean

    // wave(64) shuffle reduction
#pragma unroll
    for (int off = 32; off > 0; off >>= 1)
        loss += __shfl_down(loss, off, 64);

    __shared__ float ws[kBlock / 64];
    const int lane = threadIdx.x & 63;
    const int wid  = threadIdx.x >> 6;
    if (lane == 0) ws[wid] = loss;
    __syncthreads();
    if (threadIdx.x == 0) {
        atomicAdd(out, ws[0] + ws[1] + ws[2] + ws[3]);
    }
}

extern "C" void kernel_launch(void* const* d_in, const int* in_sizes, int n_in,
                              void* d_out, int out_size, void* d_ws, size_t ws_size,
                              hipStream_t stream) {
    const float* x   = (const float*)d_in[0];
    const int*   tgt = (const int*)d_in[1];
    float*       out = (float*)d_out;

    // d_out is poisoned 0xAA before every launch; memset node (graph-capturable,
    // the harness itself uses hipMemsetAsync) replaces the fl_zero kernel launch.
    hipMemsetAsync(out, 0, sizeof(float), stream);
    fl_main<<<kGrid, kBlock, 0, stream>>>(x, tgt, out);
}